// Round 14
// baseline (90.531 us; speedup 1.0000x reference)
//
#include <hip/hip_runtime.h>
#include <hip/hip_bf16.h>

typedef __bf16 bf16_t;
typedef __attribute__((ext_vector_type(8))) __bf16 bf16x8;
typedef __attribute__((ext_vector_type(4))) float f32x4;

#define KDIM 1152
#define NDIM 1152
#define BM 128
#define BN 192
#define BK 32
#define NIT 36                        /* K-steps of 32 */
#define NTILES 6                      /* 1152/192 */
#define A_STEP 8192                   /* BM*BK*2 bytes per (panel,ktile) */
#define A_PANEL 294912                /* BM*KDIM*2 bytes per m-panel */
#define B_STEP 12288                  /* BN*BK*2 bytes per ktile */
#define B_TILE (36 * B_STEP)          /* per n-tile panel */

__device__ __forceinline__ void gload_lds16(const void* g, void* l) {
    __builtin_amdgcn_global_load_lds(
        (const __attribute__((address_space(1))) void*)g,
        (__attribute__((address_space(3))) void*)l, 16, 0, 0);
}

// X fp32 -> bf16, pre-swizzled to the GEMM's A-fragment order:
//   16B unit u = P*18432 + T*512 + rb*64 + g*16 + r0
//   holds rows m=P*128+rb*16+r0, k=T*32+g*8 .. +7.
// A wave's (P,T,mi) fragment = contiguous 1KB -> direct global->reg loads.
__global__ void cvt_x(const float* __restrict__ X, bf16_t* __restrict__ Xb)
{
    const int u = blockIdx.x * 256 + threadIdx.x;          // < 2359296
    const int w = u >> 9;
    const int P = w / 36;
    const int T = w - P * 36;
    const int rem = u & 511;
    const int rb = rem >> 6;
    const int g = (rem >> 4) & 3;
    const int r0 = rem & 15;
    const int m = P * 128 + rb * 16 + r0;
    const int k = T * 32 + g * 8;
    const float* src = X + (size_t)m * KDIM + k;
    f32x4 lo = *(const f32x4*)src;
    f32x4 hi = *(const f32x4*)(src + 4);
    bf16x8 v;
    #pragma unroll
    for (int e = 0; e < 4; ++e) { v[e] = (__bf16)lo[e]; v[4 + e] = (__bf16)hi[e]; }
    *(bf16x8*)((char*)Xb + (size_t)u * 16) = v;
}

// Weff panel, fragment-contiguous per n-tile (BN=192) — unchanged (proven):
//   bf16 idx(n,k) = tile*221184 + (k>>5)*6144 + (nin>>4)*512 + ((k>>3)&3)*128
//                   + (nin&15)*8 + (k&7)
__global__ void build_wb(const float* __restrict__ W,
                         const float* __restrict__ bvec,
                         bf16_t* __restrict__ Bm,
                         float* __restrict__ bias)
{
    const int t = blockIdx.x * blockDim.x + threadIdx.x;
    if (t < NDIM) {
        const int o = t / 9, p = t - o * 9;
        bias[t] = bvec[p * 128 + o];
    }
    const int c = t & 127;
    const int o = (t >> 7) & 127;
    const int p = t >> 14;
    if (p >= 9) return;
    const int r = p / 3, cc = p - r * 3;
    float eff[3][3] = {{0.f,0.f,0.f},{0.f,0.f,0.f},{0.f,0.f,0.f}};
    const float* w = W + (size_t)((p * 128 + o) * 128 + c) * 9;
    #pragma unroll
    for (int i = 0; i < 3; ++i) {
        const int a = (2 + r + i) / 3;
        #pragma unroll
        for (int j = 0; j < 3; ++j) {
            const int bb = (2 + cc + j) / 3;
            eff[a][bb] += w[i * 3 + j];
        }
    }
    const int n = o * 9 + p;
    const int tile = n / BN;
    const int nin = n - tile * BN;
    #pragma unroll
    for (int a = 0; a < 3; ++a)
        #pragma unroll
        for (int bb = 0; bb < 3; ++bb) {
            const int k = c * 9 + a * 3 + bb;
            const size_t idx = (size_t)tile * (B_TILE / 2)
                             + (k >> 5) * (B_STEP / 2)
                             + (nin >> 4) * 512 + ((k >> 3) & 3) * 128
                             + (nin & 15) * 8 + (k & 7);
            Bm[idx] = (bf16_t)eff[a][bb];
        }
}

// out[16384,1152] = Xb(bf16 frag-order) * Weff(bf16) + bias.
// BM=128 x BN=192, BK=32, 4 waves (2m x 2n, wave 64x96, acc 4x6).
// A: global->reg direct (4 dwordx4/thr/step, ping-pong afA/afB, no LDS).
// B: LDS dbuf via linear gload_lds (3/thr/step).
// LDS traffic 36KB/block-iter (was 60KB): B write 12K + B read 24K.
// vmcnt ledger: entry B(t+1)[3]; issue A(t+1)[4], B(t+2)[3]; vmcnt(3)
// drains exactly B(t+1)+A(t+1); 0 only at the tail.
__launch_bounds__(256, 3)
__global__ void ind_gemm(const bf16_t* __restrict__ Xb,
                         const bf16_t* __restrict__ Bm,
                         const float* __restrict__ bias,
                         float* __restrict__ out)
{
    __shared__ char Bs[2][B_STEP];

    const int tid = threadIdx.x;
    const int lane = tid & 63;
    const int wid = tid >> 6;
    const int wm = wid >> 1;        // 0..1
    const int wn = wid & 1;         // 0..1

    // XCD swizzle: 768 blocks = 96/XCD; consecutive swz share an m-panel
    // (147KB bf16, L2-resident) across the 6 n-tiles.
    const int bid = blockIdx.x;
    const int swz = (bid & 7) * 96 + (bid >> 3);
    const int mt = swz / NTILES;
    const int nt = swz - mt * NTILES;
    const int m0 = mt * BM;

    const int fr = (lane >> 4) * 256 + (lane & 15) * 16;
    // this wave's A-frag base: frags mi=0..3 at +0,+1024,+2048,+3072
    const char* apl = (const char*)Xb + (size_t)mt * A_PANEL + wm * 4096 + fr;
    const char* bpanel = (const char*)Bm + (size_t)nt * B_TILE;

    f32x4 acc[4][6];
    #pragma unroll
    for (int i = 0; i < 4; ++i)
        #pragma unroll
        for (int j = 0; j < 6; ++j)
            acc[i][j] = (f32x4){0.f, 0.f, 0.f, 0.f};

    f32x4 afA[4], afB[4];           // ping-pong A fragment sets (raw 16B)

    #define LOADA(T, AF) do {                                               \
        const char* p_ = apl + (size_t)(T) * A_STEP;                        \
        asm volatile("global_load_dwordx4 %0, %4, off\n\t"                  \
                     "global_load_dwordx4 %1, %4, off offset:1024\n\t"      \
                     "global_load_dwordx4 %2, %4, off offset:2048\n\t"      \
                     "global_load_dwordx4 %3, %4, off offset:3072"          \
                     : "=&v"(AF[0]), "=&v"(AF[1]), "=&v"(AF[2]), "=&v"(AF[3]) \
                     : "v"(p_) : "memory");                                 \
    } while (0)

    #define GLDB(T, BUF) do {                                               \
        const char* s_ = bpanel + (size_t)(T) * B_STEP;                     \
        _Pragma("unroll")                                                   \
        for (int r_ = 0; r_ < 3; ++r_) {                                    \
            const int u_ = (tid + r_ * 256) * 16;                           \
            gload_lds16(s_ + u_, &Bs[BUF][u_]);                             \
        } } while (0)

    #define MFMA24(AF) do {                                                 \
        __builtin_amdgcn_s_setprio(1);                                      \
        _Pragma("unroll")                                                   \
        for (int mi = 0; mi < 4; ++mi) {                                    \
            const bf16x8 a_ = __builtin_bit_cast(bf16x8, AF[mi]);           \
            _Pragma("unroll")                                               \
            for (int j_ = 0; j_ < 6; ++j_)                                  \
                acc[mi][j_] = __builtin_amdgcn_mfma_f32_16x16x32_bf16(      \
                    a_, bfr[j_], acc[mi][j_], 0, 0, 0);                     \
        }                                                                   \
        __builtin_amdgcn_s_setprio(0);                                      \
    } while (0)

    #define RDB(CUR) do {                                                   \
        _Pragma("unroll")                                                   \
        for (int j_ = 0; j_ < 6; ++j_)                                      \
            bfr[j_] = *(const bf16x8*)(&Bs[CUR][(wn * 6 + j_) * 1024 + fr]); \
        asm volatile("s_waitcnt lgkmcnt(0)" ::: "memory");                  \
        __builtin_amdgcn_sched_barrier(0);                                  \
        __builtin_amdgcn_s_barrier();                                       \
    } while (0)

    bf16x8 bfr[6];

    // ---- prologue: A(0)[4], B(0)[3], B(1)[3] in flight ----
    LOADA(0, afA);
    GLDB(0, 0);
    GLDB(1, 1);
    asm volatile("s_waitcnt vmcnt(3)" ::: "memory");  // A(0)+B(0) done; B(1) flies
    __builtin_amdgcn_sched_barrier(0);
    __builtin_amdgcn_s_barrier();

    // steady state: 17 double-iters (t = 0..33)
    #pragma unroll 1
    for (int t2 = 0; t2 < 17; ++t2) {
        const int t = 2 * t2;
        // ---- even iter t (cur=0, compute afA) ----
        RDB(0);                          // read B(t), drain lgkm, barrier
        LOADA(t + 1, afB);               // +4
        GLDB(t + 2, 0);                  // +3  (buf0 safe: barrier passed)
        MFMA24(afA);
        asm volatile("s_waitcnt vmcnt(3)" ::: "memory"); // B(t+1)+A(t+1) done
        __builtin_amdgcn_sched_barrier(0);
        __builtin_amdgcn_s_barrier();
        // ---- odd iter t+1 (cur=1, compute afB) ----
        RDB(1);
        LOADA(t + 2, afA);
        GLDB(t + 3, 1);
        MFMA24(afB);
        asm volatile("s_waitcnt vmcnt(3)" ::: "memory"); // B(t+2)+A(t+2) done
        __builtin_amdgcn_sched_barrier(0);
        __builtin_amdgcn_s_barrier();
    }
    // ---- t = 34 (cur=0, afA): last prefetch, drain all ----
    RDB(0);
    LOADA(35, afB);                      // +4 ; entry B(35)[3]
    MFMA24(afA);
    asm volatile("s_waitcnt vmcnt(0)" ::: "memory");
    __builtin_amdgcn_sched_barrier(0);
    __builtin_amdgcn_s_barrier();
    // ---- t = 35 (cur=1, afB): compute-only ----
    {
        #pragma unroll
        for (int j_ = 0; j_ < 6; ++j_)
            bfr[j_] = *(const bf16x8*)(&Bs[1][(wn * 6 + j_) * 1024 + fr]);
        asm volatile("s_waitcnt lgkmcnt(0)" ::: "memory");
        __builtin_amdgcn_sched_barrier(0);
        MFMA24(afB);
    }

    #undef LOADA
    #undef GLDB
    #undef MFMA24
    #undef RDB

    // ---- epilogue: C/D col=lane&15, row=(lane>>4)*4+reg ----
    const int orow = (lane >> 4) * 4;
    const int ocol = lane & 15;
    const int gn0 = nt * BN + wn * 96 + ocol;
    #pragma unroll
    for (int ni = 0; ni < 6; ++ni) {
        const float bv = bias[gn0 + ni * 16];
        #pragma unroll
        for (int mi = 0; mi < 4; ++mi) {
            float* po = out + (size_t)(m0 + wm * 64 + mi * 16 + orow) * NDIM
                            + gn0 + ni * 16;
            #pragma unroll
            for (int r = 0; r < 4; ++r)
                po[(size_t)r * NDIM] = acc[mi][ni][r] + bv;
        }
    }
}

extern "C" void kernel_launch(void* const* d_in, const int* in_sizes, int n_in,
                              void* d_out, int out_size, void* d_ws, size_t ws_size,
                              hipStream_t stream)
{
    const float* x  = (const float*)d_in[0];
    const float* W  = (const float*)d_in[1];
    const float* bv = (const float*)d_in[2];
    float* out = (float*)d_out;

    // ws: Xb 37.75 MB | Bm 2.65 MB | bias 4.6 KB
    bf16_t* Xb   = (bf16_t*)d_ws;
    bf16_t* Bm   = (bf16_t*)((char*)d_ws + (size_t)16384 * KDIM * sizeof(bf16_t));
    float*  bias = (float*)((char*)Bm + (size_t)KDIM * NDIM * sizeof(bf16_t));

    cvt_x<<<9216, 256, 0, stream>>>(x, Xb);
    build_wb<<<576, 256, 0, stream>>>(W, bv, Bm, bias);
    ind_gemm<<<768, 256, 0, stream>>>(Xb, Bm, bias, out);
}